// Round 3
// baseline (5761.356 us; speedup 1.0000x reference)
//
#include <hip/hip_runtime.h>
#include <math.h>

#define Dd 128
#define Tt 1024
#define Kk 2048
#define Nn 65536
#define DT 131072  // Dd*Tt
#define MARGIN 1.0e-4f

typedef __attribute__((ext_vector_type(8))) short short8;
typedef __attribute__((ext_vector_type(4))) float float4v;

// ws layout (bytes):
//   cbh     @ 0        : ushort[262144] = 524288   (bf16 hi plane of codebook, [k][d])
//   cbl     @ 524288   : ushort[262144] = 524288   (bf16 lo plane)
//   e2f     @ 1048576  : float[2048]    = 8192     (np-replica fp32 ||e||^2)
//   Arow    @ 1056768  : float[65536]   = 262144   (np-replica fp32 ||x||^2)
//   idxbuf  @ 1318912  : int[65536]     = 262144
//   counts  @ 1581056  : int[2048]      = 8192
//   part    @ 1589248  : double[4096]   = 32768
//   cand_g  @ 1622016  : ushort[65536*16] = 2097152
//   candcnt @ 3719168  : int[65536]     = 262144
// total 3981312 B (~3.98 MB)

// Split codebook into bf16 hi/lo planes (RNE), zero histogram.
__global__ __launch_bounds__(256)
void prep_kernel(const float* __restrict__ cb, ushort* __restrict__ cbh,
                 ushort* __restrict__ cbl, int* __restrict__ counts) {
  const int g = blockIdx.x * 256 + threadIdx.x;   // 1024 blocks -> 262144 elems
  const float v = cb[g];
  const unsigned u = __float_as_uint(v);
  const unsigned hb = (u + 0x7FFFu + ((u >> 16) & 1u)) & 0xFFFF0000u;  // RNE bf16 (as f32 bits)
  const float vh = __uint_as_float(hb);
  const float vl = v - vh;
  const unsigned u2 = __float_as_uint(vl);
  const unsigned lb = (u2 + 0x7FFFu + ((u2 >> 16) & 1u)) >> 16;
  cbh[g] = (ushort)(hb >> 16);
  cbl[g] = (ushort)lb;
  if (g < Kk) counts[g] = 0;
}

// ||x||^2 per row, replicating numpy fp32 pairwise sum (8 accumulators).
__global__ __launch_bounds__(256)
void rowsum_kernel(const float* __restrict__ z, float* __restrict__ Arow) {
  const int g = blockIdx.x * 256 + threadIdx.x;   // 256 blocks -> 65536 rows
  const int b = g >> 10, t = g & 1023;
  const float* p = z + (size_t)b * DT + t;        // x_d = p[d*Tt]
  float r[8];
  #pragma unroll
  for (int j = 0; j < 8; ++j) {
    const float v = p[j * Tt];
    r[j] = __fmul_rn(v, v);
  }
  for (int i = 1; i < 16; ++i) {
    #pragma unroll
    for (int j = 0; j < 8; ++j) {
      const float v = p[(8 * i + j) * Tt];
      r[j] = __fadd_rn(r[j], __fmul_rn(v, v));
    }
  }
  Arow[g] = __fadd_rn(__fadd_rn(__fadd_rn(r[0], r[1]), __fadd_rn(r[2], r[3])),
                      __fadd_rn(__fadd_rn(r[4], r[5]), __fadd_rn(r[6], r[7])));
}

// ||e||^2 per code, same numpy fp32 pairwise order.
__global__ __launch_bounds__(256)
void e2f_kernel(const float* __restrict__ cb, float* __restrict__ e2f) {
  const int k = blockIdx.x * 256 + threadIdx.x;   // 8 blocks -> 2048 codes
  const float* p = cb + (size_t)k * Dd;
  float r[8];
  #pragma unroll
  for (int j = 0; j < 8; ++j) r[j] = __fmul_rn(p[j], p[j]);
  for (int i = 1; i < 16; ++i) {
    #pragma unroll
    for (int j = 0; j < 8; ++j) {
      const float v = p[8 * i + j];
      r[j] = __fadd_rn(r[j], __fmul_rn(v, v));
    }
  }
  e2f[k] = __fadd_rn(__fadd_rn(__fadd_rn(r[0], r[1]), __fadd_rn(r[2], r[3])),
                     __fadd_rn(__fadd_rn(r[4], r[5]), __fadd_rn(r[6], r[7])));
}

// Phase 1: bf16-split MFMA approximate scoring + margin-gated candidate lists.
// 64 rows/block, 32 chunks of 64 codes; wave tile 32x32 via 4x 16x16x32 MFMA tiles.
// LDS planes XOR-swizzled at 16B-block granularity: phys(e,k) =
//   e*128 + (((k>>3) ^ (e&15))<<3 | (k&7))  -> 2-way-max bank aliasing on b128 reads.
__global__ __launch_bounds__(256, 2)
void score_kernel(const float* __restrict__ z, const ushort* __restrict__ cbh,
                  const ushort* __restrict__ cbl, const float* __restrict__ e2f,
                  ushort* __restrict__ cand_g, int* __restrict__ candcnt) {
  __shared__ ushort zh[8192], zl[8192];   // 16 KB each: z planes [row][k=d]
  __shared__ ushort eh[8192], el[8192];   // 16 KB each: code planes [code][k=d]
  __shared__ char ubuf[8192];             // union: seed-reduce scratch | cnt+cand lists
  __shared__ float seed[64];
  const int tid = threadIdx.x;
  const int n0 = blockIdx.x * 64;         // 1024 blocks
  const int b = n0 >> 10, t0 = n0 & 1023;
  const float* zb = z + (size_t)b * DT + t0;
  // ---- stage z: split to bf16 hi/lo, swizzled transpose into LDS ----
  {
    const int i = tid & 63;        // row
    const int dg = tid >> 6;
    for (int j = 0; j < 32; ++j) {
      const int d = dg + 4 * j;
      const float v = zb[d * Tt + i];          // coalesced over i
      const unsigned u = __float_as_uint(v);
      const unsigned hb = (u + 0x7FFFu + ((u >> 16) & 1u)) & 0xFFFF0000u;
      const float vh = __uint_as_float(hb);
      const float vl = v - vh;
      const unsigned u2 = __float_as_uint(vl);
      const unsigned lb = (u2 + 0x7FFFu + ((u2 >> 16) & 1u)) >> 16;
      const int ph = (i << 7) + ((((d >> 3) ^ (i & 15)) << 3) | (d & 7));
      zh[ph] = (ushort)(hb >> 16);
      zl[ph] = (ushort)lb;
    }
  }
  const int lane = tid & 63, wv = tid >> 6;
  const int col = lane & 15, quad = lane >> 4;
  const int R0 = (wv >> 1) * 32, C0 = (wv & 1) * 32;
  int* cnt = (int*)ubuf;                   // 64 ints
  ushort* candL = (ushort*)(ubuf + 256);   // 64 x 16
  float* sred = (float*)ubuf;              // 64 x 32 floats (pre-append phase only)
  float runmin[8];
  #pragma unroll
  for (int s = 0; s < 8; ++s) runmin[s] = 1e30f;

  // iteration list: chunk 0 (min-only seed), then 0..31 with collection
  for (int it = 0; it <= 32; ++it) {
    const int ch = (it <= 1) ? 0 : (it - 1);
    if (it != 1) {                 // it==1 reuses chunk 0 already staged
      __syncthreads();
      #pragma unroll
      for (int sw = 0; sw < 4; ++sw) {
        const int s = sw * 256 + tid;            // 0..1023 slots of 16B
        const int c = s >> 4, kbp = s & 15;      // physical block
        const int kb = kbp ^ (c & 15);           // logical k-block to fetch
        const size_t go = ((size_t)(ch * 64 + c) << 7) + (kb << 3);
        ((uint4*)eh)[s] = *(const uint4*)(cbh + go);
        ((uint4*)el)[s] = *(const uint4*)(cbl + go);
      }
      __syncthreads();
    }
    float4v acc[2][2];
    const float4v vzero = {0.f, 0.f, 0.f, 0.f};
    #pragma unroll
    for (int rt = 0; rt < 2; ++rt)
      #pragma unroll
      for (int ct = 0; ct < 2; ++ct) acc[rt][ct] = vzero;
    #pragma unroll
    for (int ks = 0; ks < 4; ++ks) {
      const int kb = ks * 4 + quad;
      short8 ah[2], al[2], bh[2], bl[2];
      #pragma unroll
      for (int rt = 0; rt < 2; ++rt) {
        const int m = R0 + rt * 16 + col;        // m&15 == col
        const int o = (m << 7) + ((kb ^ col) << 3);
        ah[rt] = *(const short8*)&zh[o];
        al[rt] = *(const short8*)&zl[o];
      }
      #pragma unroll
      for (int ct = 0; ct < 2; ++ct) {
        const int c = C0 + ct * 16 + col;        // c&15 == col
        const int o = (c << 7) + ((kb ^ col) << 3);
        bh[ct] = *(const short8*)&eh[o];
        bl[ct] = *(const short8*)&el[o];
      }
      #pragma unroll
      for (int rt = 0; rt < 2; ++rt)
        #pragma unroll
        for (int ct = 0; ct < 2; ++ct) {
          acc[rt][ct] = __builtin_amdgcn_mfma_f32_16x16x32_bf16(ah[rt], bh[ct], acc[rt][ct], 0, 0, 0);
          acc[rt][ct] = __builtin_amdgcn_mfma_f32_16x16x32_bf16(ah[rt], bl[ct], acc[rt][ct], 0, 0, 0);
          acc[rt][ct] = __builtin_amdgcn_mfma_f32_16x16x32_bf16(al[rt], bh[ct], acc[rt][ct], 0, 0, 0);
        }
    }
    const int c0g = ch * 64;
    float e2v[2];
    #pragma unroll
    for (int ct = 0; ct < 2; ++ct) e2v[ct] = e2f[c0g + C0 + ct * 16 + col];
    if (it == 0) {
      #pragma unroll
      for (int rt = 0; rt < 2; ++rt)
        #pragma unroll
        for (int ct = 0; ct < 2; ++ct)
          #pragma unroll
          for (int r = 0; r < 4; ++r) {
            const float s = e2v[ct] - 2.0f * acc[rt][ct][r];
            runmin[rt * 4 + r] = fminf(runmin[rt * 4 + r], s);
          }
      // seed reduce: share chunk-0 min across the 32 lanes covering each row
      __syncthreads();
      #pragma unroll
      for (int rt = 0; rt < 2; ++rt)
        #pragma unroll
        for (int r = 0; r < 4; ++r)
          sred[(R0 + rt * 16 + quad * 4 + r) * 32 + (wv & 1) * 16 + col] = runmin[rt * 4 + r];
      __syncthreads();
      if (tid < 64) {
        float m = sred[tid * 32];
        for (int j = 1; j < 32; ++j) m = fminf(m, sred[tid * 32 + j]);
        seed[tid] = m;
      }
      __syncthreads();
      #pragma unroll
      for (int rt = 0; rt < 2; ++rt)
        #pragma unroll
        for (int r = 0; r < 4; ++r)
          runmin[rt * 4 + r] = seed[R0 + rt * 16 + quad * 4 + r];
      if (tid < 64) cnt[tid] = 0;
      __syncthreads();
    } else {
      #pragma unroll
      for (int rt = 0; rt < 2; ++rt)
        #pragma unroll
        for (int ct = 0; ct < 2; ++ct)
          #pragma unroll
          for (int r = 0; r < 4; ++r) {
            const float s = e2v[ct] - 2.0f * acc[rt][ct][r];
            const int slot = rt * 4 + r;
            if (s < runmin[slot] + MARGIN) {
              if (s < runmin[slot]) runmin[slot] = s;
              const int rl = R0 + rt * 16 + quad * 4 + r;
              const int kg = c0g + C0 + ct * 16 + col;
              const int pos = atomicAdd(&cnt[rl], 1);
              if (pos < 16) candL[rl * 16 + pos] = (ushort)kg;
            }
          }
    }
  }
  __syncthreads();
  if (tid < 64) {
    const int n = n0 + tid;
    candcnt[n] = cnt[tid];
    uint4* dst = (uint4*)(cand_g + (size_t)n * 16);
    const uint4* src = (const uint4*)(candL + tid * 16);
    dst[0] = src[0];
    dst[1] = src[1];
  }
}

// Phase 2: exact np-replica rescore of each row's candidates (R2-verified formula).
__global__ __launch_bounds__(256)
void rescore_kernel(const float* __restrict__ z, const float* __restrict__ cb,
                    const float* __restrict__ e2f, const float* __restrict__ Arow,
                    const ushort* __restrict__ cand_g, const int* __restrict__ candcnt,
                    int* __restrict__ idxbuf, int* __restrict__ counts,
                    float* __restrict__ out_idx) {
  const int n = blockIdx.x * 256 + threadIdx.x;   // 256 blocks
  const int c = candcnt[n];
  if (c == 0 || c > 16) return;                   // fallback kernel handles these
  const int b = n >> 10, t = n & 1023;
  const float* zb = z + (size_t)b * DT + t;
  const float A = Arow[n];
  float best = 1e30f;
  int bk = Kk;
  for (int j = 0; j < c; ++j) {
    const int k = cand_g[(size_t)n * 16 + j];
    const float* e = cb + (size_t)k * Dd;
    double acc = 0.0;
    #pragma unroll 8
    for (int d = 0; d < 128; d += 4) {
      const float4 ev = *(const float4*)(e + d);
      acc += (double)zb[(d + 0) * Tt] * (double)ev.x;
      acc += (double)zb[(d + 1) * Tt] * (double)ev.y;
      acc += (double)zb[(d + 2) * Tt] * (double)ev.z;
      acc += (double)zb[(d + 3) * Tt] * (double)ev.w;
    }
    const float m32 = (float)acc;
    const float X = __fsub_rn(A, __fmul_rn(2.0f, m32));
    const float Dq = __fadd_rn(X, e2f[k]);
    if (Dq < best || (Dq == best && k < bk)) { best = Dq; bk = k; }
  }
  idxbuf[n] = bk;
  out_idx[n] = (float)bk;
  atomicAdd(&counts[bk], 1);
}

// Fallback: full 2048-code exact scan for rows with empty/overflowed lists.
__global__ __launch_bounds__(256)
void fallback_kernel(const float* __restrict__ z, const float* __restrict__ cb,
                     const float* __restrict__ e2f, const float* __restrict__ Arow,
                     const int* __restrict__ candcnt, int* __restrict__ idxbuf,
                     int* __restrict__ counts, float* __restrict__ out_idx) {
  __shared__ float xrow[128];
  __shared__ float rs[256];
  __shared__ int rk[256];
  const int tid = threadIdx.x;
  for (int rr = 0; rr < 256; ++rr) {
    const int n = blockIdx.x * 256 + rr;          // 256 blocks
    const int c = candcnt[n];
    if (c >= 1 && c <= 16) continue;              // block-uniform branch
    const int b = n >> 10, t = n & 1023;
    if (tid < 128) xrow[tid] = z[(size_t)b * DT + (size_t)tid * Tt + t];
    __syncthreads();
    const float A = Arow[n];
    float best = 1e30f;
    int bk = Kk;
    for (int kk = tid * 8; kk < tid * 8 + 8; ++kk) {
      const float* e = cb + (size_t)kk * Dd;
      double acc = 0.0;
      for (int d = 0; d < 128; d += 4) {
        const float4 ev = *(const float4*)(e + d);
        acc += (double)xrow[d + 0] * (double)ev.x;
        acc += (double)xrow[d + 1] * (double)ev.y;
        acc += (double)xrow[d + 2] * (double)ev.z;
        acc += (double)xrow[d + 3] * (double)ev.w;
      }
      const float m32 = (float)acc;
      const float Dq = __fadd_rn(__fsub_rn(A, __fmul_rn(2.0f, m32)), e2f[kk]);
      if (Dq < best || (Dq == best && kk < bk)) { best = Dq; bk = kk; }
    }
    rs[tid] = best;
    rk[tid] = bk;
    __syncthreads();
    for (int o = 128; o > 0; o >>= 1) {
      if (tid < o) {
        if (rs[tid + o] < rs[tid] || (rs[tid + o] == rs[tid] && rk[tid + o] < rk[tid])) {
          rs[tid] = rs[tid + o];
          rk[tid] = rk[tid + o];
        }
      }
      __syncthreads();
    }
    if (tid == 0) {
      idxbuf[n] = rk[0];
      out_idx[n] = (float)rk[0];
      atomicAdd(&counts[rk[0]], 1);
    }
    __syncthreads();
  }
}

// Gather z_q into (B,D,T) layout + f64 loss partials.
__global__ __launch_bounds__(256)
void gather_kernel(const float* __restrict__ z, const float* __restrict__ cb,
                   const int* __restrict__ idxbuf, float* __restrict__ out0,
                   double* __restrict__ part) {
  const int tid = threadIdx.x;
  const size_t o0 = ((size_t)blockIdx.x * 256 + tid) * 8;  // 4096 blocks
  const int b = (int)(o0 >> 17);
  const int dt = (int)(o0 & (size_t)(DT - 1));
  const int d = dt >> 10;
  const int t = dt & 1023;
  const int n = (b << 10) + t;
  const float4 z0 = *(const float4*)(z + o0);
  const float4 z1 = *(const float4*)(z + o0 + 4);
  float q[8];
  #pragma unroll
  for (int j = 0; j < 8; ++j) q[j] = cb[(size_t)idxbuf[n + j] * Dd + d];
  *(float4*)(out0 + o0)     = make_float4(q[0], q[1], q[2], q[3]);
  *(float4*)(out0 + o0 + 4) = make_float4(q[4], q[5], q[6], q[7]);
  const float zz[8] = {z0.x, z0.y, z0.z, z0.w, z1.x, z1.y, z1.z, z1.w};
  double s = 0.0;
  #pragma unroll
  for (int j = 0; j < 8; ++j) {
    const double dif = (double)zz[j] - (double)q[j];
    s += dif * dif;
  }
  #pragma unroll
  for (int o = 32; o > 0; o >>= 1) s += __shfl_down(s, o, 64);
  __shared__ double w4[4];
  if ((tid & 63) == 0) w4[tid >> 6] = s;
  __syncthreads();
  if (tid == 0) part[blockIdx.x] = w4[0] + w4[1] + w4[2] + w4[3];
}

__global__ __launch_bounds__(256)
void finalize_kernel(const int* __restrict__ counts, const double* __restrict__ part,
                     float* __restrict__ out) {
  const int tid = threadIdx.x;
  __shared__ double red[256];
  double s = 0.0;
  for (int i = tid; i < 4096; i += 256) s += part[i];
  red[tid] = s;
  __syncthreads();
  for (int o = 128; o > 0; o >>= 1) {
    if (tid < o) red[tid] += red[tid + o];
    __syncthreads();
  }
  const double loss = red[0];
  __syncthreads();
  double e = 0.0;
  for (int k = tid; k < 2048; k += 256) {
    const double p = (double)counts[k] / 65536.0;
    e += p * log(p + 1e-10);
  }
  red[tid] = e;
  __syncthreads();
  for (int o = 128; o > 0; o >>= 1) {
    if (tid < o) red[tid] += red[tid + o];
    __syncthreads();
  }
  if (tid == 0) {
    out[8388608] = (float)(0.25 * loss / 8388608.0);
    out[8388609] = (float)exp(-red[0]);
  }
}

extern "C" void kernel_launch(void* const* d_in, const int* in_sizes, int n_in,
                              void* d_out, int out_size, void* d_ws, size_t ws_size,
                              hipStream_t stream) {
  const float* z = (const float*)d_in[0];      // (B, D, T) fp32
  const float* cb = (const float*)d_in[1];     // (K, D) fp32
  float* out = (float*)d_out;                  // [z_q (8388608) | loss | perp | idx (65536)]
  char* ws = (char*)d_ws;
  ushort* cbh   = (ushort*)ws;
  ushort* cbl   = (ushort*)(ws + 524288);
  float* e2f    = (float*)(ws + 1048576);
  float* Arow   = (float*)(ws + 1056768);
  int* idxbuf   = (int*)(ws + 1318912);
  int* counts   = (int*)(ws + 1581056);
  double* part  = (double*)(ws + 1589248);
  ushort* cand_g = (ushort*)(ws + 1622016);
  int* candcnt  = (int*)(ws + 3719168);

  hipLaunchKernelGGL(prep_kernel,     dim3(1024), dim3(256), 0, stream, cb, cbh, cbl, counts);
  hipLaunchKernelGGL(e2f_kernel,      dim3(8),    dim3(256), 0, stream, cb, e2f);
  hipLaunchKernelGGL(rowsum_kernel,   dim3(256),  dim3(256), 0, stream, z, Arow);
  hipLaunchKernelGGL(score_kernel,    dim3(1024), dim3(256), 0, stream, z, cbh, cbl, e2f,
                     cand_g, candcnt);
  hipLaunchKernelGGL(rescore_kernel,  dim3(256),  dim3(256), 0, stream, z, cb, e2f, Arow,
                     cand_g, candcnt, idxbuf, counts, out + 8388610);
  hipLaunchKernelGGL(fallback_kernel, dim3(256),  dim3(256), 0, stream, z, cb, e2f, Arow,
                     candcnt, idxbuf, counts, out + 8388610);
  hipLaunchKernelGGL(gather_kernel,   dim3(4096), dim3(256), 0, stream, z, cb, idxbuf, out, part);
  hipLaunchKernelGGL(finalize_kernel, dim3(1),    dim3(256), 0, stream, counts, part, out);
}

// Round 4
// 362.075 us; speedup vs baseline: 15.9120x; 15.9120x over previous
//
#include <hip/hip_runtime.h>
#include <math.h>

#define Dd 128
#define Tt 1024
#define Kk 2048
#define Nn 65536
#define DT 131072  // Dd*Tt
#define MARGIN 8.0e-4f

typedef __attribute__((ext_vector_type(8))) short short8;
typedef __attribute__((ext_vector_type(4))) float float4v;

// ws layout (bytes):
//   cbh     @ 0        : ushort[262144] = 524288   (bf16 hi plane of codebook, [k][d])
//   cbl     @ 524288   : ushort[262144] = 524288   (bf16 lo plane)
//   e2f     @ 1048576  : float[2048]    = 8192     (np-replica fp32 ||e||^2)
//   Arow    @ 1056768  : float[65536]   = 262144   (np-replica fp32 ||x||^2)
//   idxbuf  @ 1318912  : int[65536]     = 262144
//   counts  @ 1581056  : int[2048]      = 8192
//   part    @ 1589248  : double[4096]   = 32768
//   cand_g  @ 1622016  : ushort[65536*16] = 2097152
//   candcnt @ 3719168  : int[65536]     = 262144
// total 3981312 B (~3.98 MB)

// Split codebook into bf16 hi/lo planes (RNE), zero histogram.
__global__ __launch_bounds__(256)
void prep_kernel(const float* __restrict__ cb, ushort* __restrict__ cbh,
                 ushort* __restrict__ cbl, int* __restrict__ counts) {
  const int g = blockIdx.x * 256 + threadIdx.x;   // 1024 blocks -> 262144 elems
  const float v = cb[g];
  const unsigned u = __float_as_uint(v);
  const unsigned hb = (u + 0x7FFFu + ((u >> 16) & 1u)) & 0xFFFF0000u;  // RNE bf16 (as f32 bits)
  const float vh = __uint_as_float(hb);
  const float vl = v - vh;
  const unsigned u2 = __float_as_uint(vl);
  const unsigned lb = (u2 + 0x7FFFu + ((u2 >> 16) & 1u)) >> 16;
  cbh[g] = (ushort)(hb >> 16);
  cbl[g] = (ushort)lb;
  if (g < Kk) counts[g] = 0;
}

// ||x||^2 per row, replicating numpy fp32 pairwise sum (8 accumulators).
__global__ __launch_bounds__(256)
void rowsum_kernel(const float* __restrict__ z, float* __restrict__ Arow) {
  const int g = blockIdx.x * 256 + threadIdx.x;   // 256 blocks -> 65536 rows
  const int b = g >> 10, t = g & 1023;
  const float* p = z + (size_t)b * DT + t;        // x_d = p[d*Tt]
  float r[8];
  #pragma unroll
  for (int j = 0; j < 8; ++j) {
    const float v = p[j * Tt];
    r[j] = __fmul_rn(v, v);
  }
  for (int i = 1; i < 16; ++i) {
    #pragma unroll
    for (int j = 0; j < 8; ++j) {
      const float v = p[(8 * i + j) * Tt];
      r[j] = __fadd_rn(r[j], __fmul_rn(v, v));
    }
  }
  Arow[g] = __fadd_rn(__fadd_rn(__fadd_rn(r[0], r[1]), __fadd_rn(r[2], r[3])),
                      __fadd_rn(__fadd_rn(r[4], r[5]), __fadd_rn(r[6], r[7])));
}

// ||e||^2 per code, same numpy fp32 pairwise order.
__global__ __launch_bounds__(256)
void e2f_kernel(const float* __restrict__ cb, float* __restrict__ e2f) {
  const int k = blockIdx.x * 256 + threadIdx.x;   // 8 blocks -> 2048 codes
  const float* p = cb + (size_t)k * Dd;
  float r[8];
  #pragma unroll
  for (int j = 0; j < 8; ++j) r[j] = __fmul_rn(p[j], p[j]);
  for (int i = 1; i < 16; ++i) {
    #pragma unroll
    for (int j = 0; j < 8; ++j) {
      const float v = p[8 * i + j];
      r[j] = __fadd_rn(r[j], __fmul_rn(v, v));
    }
  }
  e2f[k] = __fadd_rn(__fadd_rn(__fadd_rn(r[0], r[1]), __fadd_rn(r[2], r[3])),
                     __fadd_rn(__fadd_rn(r[4], r[5]), __fadd_rn(r[6], r[7])));
}

// Phase 1: two-sweep bf16 MFMA scoring.
//  Sweep A: hi-plane-only MFMA -> per-lane min -> LDS reduce -> row-global min.
//  Sweep B: 3-term split MFMA; append codes with s < rowmin + MARGIN.
// 64 rows/block, 32 chunks of 64 codes; wave tile 32x32 via 4x 16x16x32 MFMA tiles.
// LDS planes XOR-swizzled at 16B granularity (2-way-max bank aliasing on b128).
__global__ __launch_bounds__(256, 2)
void score_kernel(const float* __restrict__ z, const ushort* __restrict__ cbh,
                  const ushort* __restrict__ cbl, const float* __restrict__ e2f,
                  ushort* __restrict__ cand_g, int* __restrict__ candcnt) {
  __shared__ ushort zh[8192], zl[8192];   // 16 KB each: z planes [row][k=d]
  __shared__ ushort eh[8192], el[8192];   // 16 KB each: code planes [code][k=d]
  __shared__ char ubuf[8192];             // union: min-reduce scratch | cnt+cand lists
  __shared__ float seed[64];
  const int tid = threadIdx.x;
  const int n0 = blockIdx.x * 64;         // 1024 blocks
  const int b = n0 >> 10, t0 = n0 & 1023;
  const float* zb = z + (size_t)b * DT + t0;
  // ---- stage z: split to bf16 hi/lo, swizzled transpose into LDS ----
  {
    const int i = tid & 63;        // row
    const int dg = tid >> 6;
    for (int j = 0; j < 32; ++j) {
      const int d = dg + 4 * j;
      const float v = zb[d * Tt + i];          // coalesced over i
      const unsigned u = __float_as_uint(v);
      const unsigned hb = (u + 0x7FFFu + ((u >> 16) & 1u)) & 0xFFFF0000u;
      const float vh = __uint_as_float(hb);
      const float vl = v - vh;
      const unsigned u2 = __float_as_uint(vl);
      const unsigned lb = (u2 + 0x7FFFu + ((u2 >> 16) & 1u)) >> 16;
      const int ph = (i << 7) + ((((d >> 3) ^ (i & 15)) << 3) | (d & 7));
      zh[ph] = (ushort)(hb >> 16);
      zl[ph] = (ushort)lb;
    }
  }
  const int lane = tid & 63, wv = tid >> 6;
  const int col = lane & 15, quad = lane >> 4;
  const int R0 = (wv >> 1) * 32, C0 = (wv & 1) * 32;
  int* cnt = (int*)ubuf;                   // 64 ints
  ushort* candL = (ushort*)(ubuf + 256);   // 64 x 16
  float* sred = (float*)ubuf;              // 64 x 32 floats (between sweeps only)
  const float4v vzero = {0.f, 0.f, 0.f, 0.f};
  float runmin[8];
  #pragma unroll
  for (int s = 0; s < 8; ++s) runmin[s] = 1e30f;

  // ---- Sweep A: hi-only coarse min ----
  for (int ch = 0; ch < 32; ++ch) {
    __syncthreads();
    #pragma unroll
    for (int sw = 0; sw < 4; ++sw) {
      const int s = sw * 256 + tid;            // 0..1023 slots of 16B
      const int c = s >> 4, kbp = s & 15;      // physical block
      const int kb = kbp ^ (c & 15);           // logical k-block to fetch
      const size_t go = ((size_t)(ch * 64 + c) << 7) + (kb << 3);
      ((uint4*)eh)[s] = *(const uint4*)(cbh + go);
    }
    __syncthreads();
    float4v acc[2][2];
    #pragma unroll
    for (int rt = 0; rt < 2; ++rt)
      #pragma unroll
      for (int ct = 0; ct < 2; ++ct) acc[rt][ct] = vzero;
    #pragma unroll
    for (int ks = 0; ks < 4; ++ks) {
      const int kb = ks * 4 + quad;
      short8 ah[2], bh[2];
      #pragma unroll
      for (int rt = 0; rt < 2; ++rt) {
        const int m = R0 + rt * 16 + col;
        ah[rt] = *(const short8*)&zh[(m << 7) + ((kb ^ col) << 3)];
      }
      #pragma unroll
      for (int ct = 0; ct < 2; ++ct) {
        const int c = C0 + ct * 16 + col;
        bh[ct] = *(const short8*)&eh[(c << 7) + ((kb ^ col) << 3)];
      }
      #pragma unroll
      for (int rt = 0; rt < 2; ++rt)
        #pragma unroll
        for (int ct = 0; ct < 2; ++ct)
          acc[rt][ct] = __builtin_amdgcn_mfma_f32_16x16x32_bf16(ah[rt], bh[ct], acc[rt][ct], 0, 0, 0);
    }
    const int c0g = ch * 64;
    #pragma unroll
    for (int ct = 0; ct < 2; ++ct) {
      const float e2v = e2f[c0g + C0 + ct * 16 + col];
      #pragma unroll
      for (int rt = 0; rt < 2; ++rt)
        #pragma unroll
        for (int r = 0; r < 4; ++r) {
          const float s = e2v - 2.0f * acc[rt][ct][r];
          runmin[rt * 4 + r] = fminf(runmin[rt * 4 + r], s);
        }
    }
  }
  // ---- row-global min reduce (32 lanes per row across 2 waves) ----
  __syncthreads();
  #pragma unroll
  for (int rt = 0; rt < 2; ++rt)
    #pragma unroll
    for (int r = 0; r < 4; ++r)
      sred[(R0 + rt * 16 + quad * 4 + r) * 32 + (wv & 1) * 16 + col] = runmin[rt * 4 + r];
  __syncthreads();
  if (tid < 64) {
    float m = sred[tid * 32];
    for (int j = 1; j < 32; ++j) m = fminf(m, sred[tid * 32 + j]);
    seed[tid] = m;
  }
  __syncthreads();
  float thresh[8];
  #pragma unroll
  for (int rt = 0; rt < 2; ++rt)
    #pragma unroll
    for (int r = 0; r < 4; ++r)
      thresh[rt * 4 + r] = seed[R0 + rt * 16 + quad * 4 + r] + MARGIN;
  if (tid < 64) cnt[tid] = 0;

  // ---- Sweep B: 3-term split, margin-gated append ----
  for (int ch = 0; ch < 32; ++ch) {
    __syncthreads();
    #pragma unroll
    for (int sw = 0; sw < 4; ++sw) {
      const int s = sw * 256 + tid;
      const int c = s >> 4, kbp = s & 15;
      const int kb = kbp ^ (c & 15);
      const size_t go = ((size_t)(ch * 64 + c) << 7) + (kb << 3);
      ((uint4*)eh)[s] = *(const uint4*)(cbh + go);
      ((uint4*)el)[s] = *(const uint4*)(cbl + go);
    }
    __syncthreads();
    float4v acc[2][2];
    #pragma unroll
    for (int rt = 0; rt < 2; ++rt)
      #pragma unroll
      for (int ct = 0; ct < 2; ++ct) acc[rt][ct] = vzero;
    #pragma unroll
    for (int ks = 0; ks < 4; ++ks) {
      const int kb = ks * 4 + quad;
      short8 ah[2], al[2], bh[2], bl[2];
      #pragma unroll
      for (int rt = 0; rt < 2; ++rt) {
        const int m = R0 + rt * 16 + col;
        const int o = (m << 7) + ((kb ^ col) << 3);
        ah[rt] = *(const short8*)&zh[o];
        al[rt] = *(const short8*)&zl[o];
      }
      #pragma unroll
      for (int ct = 0; ct < 2; ++ct) {
        const int c = C0 + ct * 16 + col;
        const int o = (c << 7) + ((kb ^ col) << 3);
        bh[ct] = *(const short8*)&eh[o];
        bl[ct] = *(const short8*)&el[o];
      }
      #pragma unroll
      for (int rt = 0; rt < 2; ++rt)
        #pragma unroll
        for (int ct = 0; ct < 2; ++ct) {
          acc[rt][ct] = __builtin_amdgcn_mfma_f32_16x16x32_bf16(ah[rt], bh[ct], acc[rt][ct], 0, 0, 0);
          acc[rt][ct] = __builtin_amdgcn_mfma_f32_16x16x32_bf16(ah[rt], bl[ct], acc[rt][ct], 0, 0, 0);
          acc[rt][ct] = __builtin_amdgcn_mfma_f32_16x16x32_bf16(al[rt], bh[ct], acc[rt][ct], 0, 0, 0);
        }
    }
    const int c0g = ch * 64;
    #pragma unroll
    for (int ct = 0; ct < 2; ++ct) {
      const float e2v = e2f[c0g + C0 + ct * 16 + col];
      const int kg0 = c0g + C0 + ct * 16 + col;
      #pragma unroll
      for (int rt = 0; rt < 2; ++rt)
        #pragma unroll
        for (int r = 0; r < 4; ++r) {
          const float s = e2v - 2.0f * acc[rt][ct][r];
          const int slot = rt * 4 + r;
          if (s < thresh[slot]) {
            const int rl = R0 + rt * 16 + quad * 4 + r;
            const int pos = atomicAdd(&cnt[rl], 1);
            if (pos < 16) candL[rl * 16 + pos] = (ushort)kg0;
          }
        }
    }
  }
  __syncthreads();
  if (tid < 64) {
    const int n = n0 + tid;
    candcnt[n] = cnt[tid];
    uint4* dst = (uint4*)(cand_g + (size_t)n * 16);
    const uint4* src = (const uint4*)(candL + tid * 16);
    dst[0] = src[0];
    dst[1] = src[1];
  }
}

// Phase 2: exact np-replica rescore of each row's candidates (R2-verified formula).
__global__ __launch_bounds__(256)
void rescore_kernel(const float* __restrict__ z, const float* __restrict__ cb,
                    const float* __restrict__ e2f, const float* __restrict__ Arow,
                    const ushort* __restrict__ cand_g, const int* __restrict__ candcnt,
                    int* __restrict__ idxbuf, int* __restrict__ counts,
                    float* __restrict__ out_idx) {
  const int n = blockIdx.x * 256 + threadIdx.x;   // 256 blocks
  const int c = candcnt[n];
  if (c == 0 || c > 16) return;                   // fallback kernel handles these
  const int b = n >> 10, t = n & 1023;
  const float* zb = z + (size_t)b * DT + t;
  const float A = Arow[n];
  float best = 1e30f;
  int bk = Kk;
  for (int j = 0; j < c; ++j) {
    const int k = cand_g[(size_t)n * 16 + j];
    const float* e = cb + (size_t)k * Dd;
    double acc = 0.0;
    #pragma unroll 8
    for (int d = 0; d < 128; d += 4) {
      const float4 ev = *(const float4*)(e + d);
      acc += (double)zb[(d + 0) * Tt] * (double)ev.x;
      acc += (double)zb[(d + 1) * Tt] * (double)ev.y;
      acc += (double)zb[(d + 2) * Tt] * (double)ev.z;
      acc += (double)zb[(d + 3) * Tt] * (double)ev.w;
    }
    const float m32 = (float)acc;
    const float X = __fsub_rn(A, __fmul_rn(2.0f, m32));
    const float Dq = __fadd_rn(X, e2f[k]);
    if (Dq < best || (Dq == best && k < bk)) { best = Dq; bk = k; }
  }
  idxbuf[n] = bk;
  out_idx[n] = (float)bk;
  atomicAdd(&counts[bk], 1);
}

// Fallback: full exact scan for rows with empty/overflowed lists (expected: none).
__global__ __launch_bounds__(256)
void fallback_kernel(const float* __restrict__ z, const float* __restrict__ cb,
                     const float* __restrict__ e2f, const float* __restrict__ Arow,
                     const int* __restrict__ candcnt, int* __restrict__ idxbuf,
                     int* __restrict__ counts, float* __restrict__ out_idx) {
  __shared__ int flags[256];
  __shared__ int nf;
  __shared__ float xrow[128];
  __shared__ float rs[256];
  __shared__ int rk[256];
  const int tid = threadIdx.x;
  const int nb = blockIdx.x * 256;                // 256 blocks
  if (tid == 0) nf = 0;
  __syncthreads();
  const int c = candcnt[nb + tid];
  const int bad = (c < 1 || c > 16) ? 1 : 0;
  flags[tid] = bad;
  if (bad) atomicAdd(&nf, 1);
  __syncthreads();
  if (nf == 0) return;                            // fast path: ~2 us total
  for (int rr = 0; rr < 256; ++rr) {
    if (!flags[rr]) continue;                     // block-uniform
    const int n = nb + rr;
    const int b = n >> 10, t = n & 1023;
    if (tid < 128) xrow[tid] = z[(size_t)b * DT + (size_t)tid * Tt + t];
    __syncthreads();
    const float A = Arow[n];
    float best = 1e30f;
    int bk = Kk;
    for (int kk = tid * 8; kk < tid * 8 + 8; ++kk) {
      const float* e = cb + (size_t)kk * Dd;
      double acc = 0.0;
      for (int d = 0; d < 128; d += 4) {
        const float4 ev = *(const float4*)(e + d);
        acc += (double)xrow[d + 0] * (double)ev.x;
        acc += (double)xrow[d + 1] * (double)ev.y;
        acc += (double)xrow[d + 2] * (double)ev.z;
        acc += (double)xrow[d + 3] * (double)ev.w;
      }
      const float m32 = (float)acc;
      const float Dq = __fadd_rn(__fsub_rn(A, __fmul_rn(2.0f, m32)), e2f[kk]);
      if (Dq < best || (Dq == best && kk < bk)) { best = Dq; bk = kk; }
    }
    rs[tid] = best;
    rk[tid] = bk;
    __syncthreads();
    for (int o = 128; o > 0; o >>= 1) {
      if (tid < o) {
        if (rs[tid + o] < rs[tid] || (rs[tid + o] == rs[tid] && rk[tid + o] < rk[tid])) {
          rs[tid] = rs[tid + o];
          rk[tid] = rk[tid + o];
        }
      }
      __syncthreads();
    }
    if (tid == 0) {
      idxbuf[n] = rk[0];
      out_idx[n] = (float)rk[0];
      atomicAdd(&counts[rk[0]], 1);
    }
    __syncthreads();
  }
}

// Gather z_q into (B,D,T) layout + f64 loss partials.
__global__ __launch_bounds__(256)
void gather_kernel(const float* __restrict__ z, const float* __restrict__ cb,
                   const int* __restrict__ idxbuf, float* __restrict__ out0,
                   double* __restrict__ part) {
  const int tid = threadIdx.x;
  const size_t o0 = ((size_t)blockIdx.x * 256 + tid) * 8;  // 4096 blocks
  const int b = (int)(o0 >> 17);
  const int dt = (int)(o0 & (size_t)(DT - 1));
  const int d = dt >> 10;
  const int t = dt & 1023;
  const int n = (b << 10) + t;
  const float4 z0 = *(const float4*)(z + o0);
  const float4 z1 = *(const float4*)(z + o0 + 4);
  float q[8];
  #pragma unroll
  for (int j = 0; j < 8; ++j) q[j] = cb[(size_t)idxbuf[n + j] * Dd + d];
  *(float4*)(out0 + o0)     = make_float4(q[0], q[1], q[2], q[3]);
  *(float4*)(out0 + o0 + 4) = make_float4(q[4], q[5], q[6], q[7]);
  const float zz[8] = {z0.x, z0.y, z0.z, z0.w, z1.x, z1.y, z1.z, z1.w};
  double s = 0.0;
  #pragma unroll
  for (int j = 0; j < 8; ++j) {
    const double dif = (double)zz[j] - (double)q[j];
    s += dif * dif;
  }
  #pragma unroll
  for (int o = 32; o > 0; o >>= 1) s += __shfl_down(s, o, 64);
  __shared__ double w4[4];
  if ((tid & 63) == 0) w4[tid >> 6] = s;
  __syncthreads();
  if (tid == 0) part[blockIdx.x] = w4[0] + w4[1] + w4[2] + w4[3];
}

__global__ __launch_bounds__(256)
void finalize_kernel(const int* __restrict__ counts, const double* __restrict__ part,
                     float* __restrict__ out) {
  const int tid = threadIdx.x;
  __shared__ double red[256];
  double s = 0.0;
  for (int i = tid; i < 4096; i += 256) s += part[i];
  red[tid] = s;
  __syncthreads();
  for (int o = 128; o > 0; o >>= 1) {
    if (tid < o) red[tid] += red[tid + o];
    __syncthreads();
  }
  const double loss = red[0];
  __syncthreads();
  double e = 0.0;
  for (int k = tid; k < 2048; k += 256) {
    const double p = (double)counts[k] / 65536.0;
    e += p * log(p + 1e-10);
  }
  red[tid] = e;
  __syncthreads();
  for (int o = 128; o > 0; o >>= 1) {
    if (tid < o) red[tid] += red[tid + o];
    __syncthreads();
  }
  if (tid == 0) {
    out[8388608] = (float)(0.25 * loss / 8388608.0);
    out[8388609] = (float)exp(-red[0]);
  }
}

extern "C" void kernel_launch(void* const* d_in, const int* in_sizes, int n_in,
                              void* d_out, int out_size, void* d_ws, size_t ws_size,
                              hipStream_t stream) {
  const float* z = (const float*)d_in[0];      // (B, D, T) fp32
  const float* cb = (const float*)d_in[1];     // (K, D) fp32
  float* out = (float*)d_out;                  // [z_q (8388608) | loss | perp | idx (65536)]
  char* ws = (char*)d_ws;
  ushort* cbh   = (ushort*)ws;
  ushort* cbl   = (ushort*)(ws + 524288);
  float* e2f    = (float*)(ws + 1048576);
  float* Arow   = (float*)(ws + 1056768);
  int* idxbuf   = (int*)(ws + 1318912);
  int* counts   = (int*)(ws + 1581056);
  double* part  = (double*)(ws + 1589248);
  ushort* cand_g = (ushort*)(ws + 1622016);
  int* candcnt  = (int*)(ws + 3719168);

  hipLaunchKernelGGL(prep_kernel,     dim3(1024), dim3(256), 0, stream, cb, cbh, cbl, counts);
  hipLaunchKernelGGL(e2f_kernel,      dim3(8),    dim3(256), 0, stream, cb, e2f);
  hipLaunchKernelGGL(rowsum_kernel,   dim3(256),  dim3(256), 0, stream, z, Arow);
  hipLaunchKernelGGL(score_kernel,    dim3(1024), dim3(256), 0, stream, z, cbh, cbl, e2f,
                     cand_g, candcnt);
  hipLaunchKernelGGL(rescore_kernel,  dim3(256),  dim3(256), 0, stream, z, cb, e2f, Arow,
                     cand_g, candcnt, idxbuf, counts, out + 8388610);
  hipLaunchKernelGGL(fallback_kernel, dim3(256),  dim3(256), 0, stream, z, cb, e2f, Arow,
                     candcnt, idxbuf, counts, out + 8388610);
  hipLaunchKernelGGL(gather_kernel,   dim3(4096), dim3(256), 0, stream, z, cb, idxbuf, out, part);
  hipLaunchKernelGGL(finalize_kernel, dim3(1),    dim3(256), 0, stream, counts, part, out);
}

// Round 5
// 332.251 us; speedup vs baseline: 17.3404x; 1.0898x over previous
//
#include <hip/hip_runtime.h>
#include <math.h>

#define Dd 128
#define Tt 1024
#define Kk 2048
#define Nn 65536
#define DT 131072  // Dd*Tt

typedef __attribute__((ext_vector_type(8))) short short8;
typedef __attribute__((ext_vector_type(4))) float float4v;

// ws layout (bytes):
//   cbh     @ 0        : ushort[262144] = 524288   (bf16 hi plane of codebook, [k][d])
//   e2f     @ 524288   : float[2048]    = 8192     (np-replica fp32 ||e||^2)
//   Arow    @ 532480   : float[65536]   = 262144   (np-replica fp32 ||x||^2)
//   idxbuf  @ 794624   : int[65536]     = 262144
//   counts  @ 1056768  : int[2048]      = 8192
//   part    @ 1064960  : double[512]    = 4096
//   cand_g  @ 1069056  : ushort[65536*16] = 2097152
//   candcnt @ 3166208  : int[65536]     = 262144
// total 3428352 B (~3.43 MB)

// Fused setup: bf16-hi split of codebook + zero histogram (blocks 0..1023),
// np-replica fp32 ||e||^2 (blocks 1024..1031), np-replica fp32 ||x||^2
// (blocks 1032..1287). numpy pairwise order for n=128: 8 accumulators,
// sequential i, combine ((r0+r1)+(r2+r3))+((r4+r5)+(r6+r7)); __f*_rn blocks
// FMA contraction so each square rounds like numpy's flat*flat.
__global__ __launch_bounds__(256)
void setup_kernel(const float* __restrict__ cb, const float* __restrict__ z,
                  ushort* __restrict__ cbh, float* __restrict__ e2f,
                  float* __restrict__ Arow, int* __restrict__ counts) {
  const int bid = blockIdx.x, tid = threadIdx.x;
  if (bid < 1024) {
    const int g = bid * 256 + tid;                // 262144 codebook elems
    const float v = cb[g];
    const unsigned u = __float_as_uint(v);
    const unsigned hb = (u + 0x7FFFu + ((u >> 16) & 1u)) & 0xFFFF0000u;  // RNE bf16
    cbh[g] = (ushort)(hb >> 16);
    if (g < Kk) counts[g] = 0;
  } else if (bid < 1032) {
    const int k = (bid - 1024) * 256 + tid;       // 2048 codes
    const float* p = cb + (size_t)k * Dd;
    float r[8];
    #pragma unroll
    for (int j = 0; j < 8; ++j) r[j] = __fmul_rn(p[j], p[j]);
    for (int i = 1; i < 16; ++i) {
      #pragma unroll
      for (int j = 0; j < 8; ++j) {
        const float v = p[8 * i + j];
        r[j] = __fadd_rn(r[j], __fmul_rn(v, v));
      }
    }
    e2f[k] = __fadd_rn(__fadd_rn(__fadd_rn(r[0], r[1]), __fadd_rn(r[2], r[3])),
                       __fadd_rn(__fadd_rn(r[4], r[5]), __fadd_rn(r[6], r[7])));
  } else {
    const int g = (bid - 1032) * 256 + tid;       // 65536 rows
    const int b = g >> 10, t = g & 1023;
    const float* p = z + (size_t)b * DT + t;      // x_d = p[d*Tt]
    float r[8];
    #pragma unroll
    for (int j = 0; j < 8; ++j) {
      const float v = p[j * Tt];
      r[j] = __fmul_rn(v, v);
    }
    for (int i = 1; i < 16; ++i) {
      #pragma unroll
      for (int j = 0; j < 8; ++j) {
        const float v = p[(8 * i + j) * Tt];
        r[j] = __fadd_rn(r[j], __fmul_rn(v, v));
      }
    }
    Arow[g] = __fadd_rn(__fadd_rn(__fadd_rn(r[0], r[1]), __fadd_rn(r[2], r[3])),
                        __fadd_rn(__fadd_rn(r[4], r[5]), __fadd_rn(r[6], r[7])));
  }
}

// Phase 1: two-sweep hi-plane-only bf16 MFMA scoring.
//  Sweep A: per-lane min -> LDS reduce -> row-global min m.
//  Sweep B: identical recompute (bitwise equal); append codes with
//           s < m + margin_row, margin_row = 8.7e-5*sqrt(Arow) + 1e-4
//           (deterministic bound: 2*(4*2^-9*||x||*||e||max) + fp32-quant).
// 64 rows/block, 32 chunks of 64 codes; wave tile 32x32 via 4x 16x16x32 MFMA.
// LDS XOR-swizzled at 16B granularity; 41.5 KB -> 3 blocks/CU.
__global__ __launch_bounds__(256, 3)
void score_kernel(const float* __restrict__ z, const ushort* __restrict__ cbh,
                  const float* __restrict__ e2f, const float* __restrict__ Arow,
                  ushort* __restrict__ cand_g, int* __restrict__ candcnt) {
  __shared__ ushort zh[8192];             // 16 KB: z hi plane [row][k=d]
  __shared__ ushort eh[8192];             // 16 KB: code hi plane [code][k=d]
  __shared__ char ubuf[8192];             // union: min-reduce scratch | cnt+cand lists
  __shared__ float seed[64];
  __shared__ float marg[64];
  const int tid = threadIdx.x;
  const int n0 = blockIdx.x * 64;         // 1024 blocks
  const int b = n0 >> 10, t0 = n0 & 1023;
  const float* zb = z + (size_t)b * DT + t0;
  // ---- stage z hi plane: swizzled transpose into LDS ----
  {
    const int i = tid & 63;        // row
    const int dg = tid >> 6;
    for (int j = 0; j < 32; ++j) {
      const int d = dg + 4 * j;
      const float v = zb[d * Tt + i];          // coalesced over i
      const unsigned u = __float_as_uint(v);
      const unsigned hb = (u + 0x7FFFu + ((u >> 16) & 1u)) & 0xFFFF0000u;
      const int ph = (i << 7) + ((((d >> 3) ^ (i & 15)) << 3) | (d & 7));
      zh[ph] = (ushort)(hb >> 16);
    }
  }
  if (tid < 64) marg[tid] = 8.7e-5f * sqrtf(Arow[n0 + tid]) + 1.0e-4f;
  const int lane = tid & 63, wv = tid >> 6;
  const int col = lane & 15, quad = lane >> 4;
  const int R0 = (wv >> 1) * 32, C0 = (wv & 1) * 32;
  int* cnt = (int*)ubuf;                   // 64 ints
  ushort* candL = (ushort*)(ubuf + 256);   // 64 x 16
  float* sred = (float*)ubuf;              // 64 x 32 floats (between sweeps only)
  const float4v vzero = {0.f, 0.f, 0.f, 0.f};
  float runmin[8];
  #pragma unroll
  for (int s = 0; s < 8; ++s) runmin[s] = 1e30f;

  // ---- Sweep A: row-global coarse min ----
  for (int ch = 0; ch < 32; ++ch) {
    __syncthreads();
    #pragma unroll
    for (int sw = 0; sw < 4; ++sw) {
      const int s = sw * 256 + tid;            // 0..1023 slots of 16B
      const int c = s >> 4, kbp = s & 15;      // physical block
      const int kb = kbp ^ (c & 15);           // logical k-block to fetch
      ((uint4*)eh)[s] = *(const uint4*)(cbh + (((size_t)(ch * 64 + c)) << 7) + (kb << 3));
    }
    __syncthreads();
    float4v acc[2][2];
    #pragma unroll
    for (int rt = 0; rt < 2; ++rt)
      #pragma unroll
      for (int ct = 0; ct < 2; ++ct) acc[rt][ct] = vzero;
    #pragma unroll
    for (int ks = 0; ks < 4; ++ks) {
      const int kb = ks * 4 + quad;
      short8 ah[2], bh[2];
      #pragma unroll
      for (int rt = 0; rt < 2; ++rt)
        ah[rt] = *(const short8*)&zh[((R0 + rt * 16 + col) << 7) + ((kb ^ col) << 3)];
      #pragma unroll
      for (int ct = 0; ct < 2; ++ct)
        bh[ct] = *(const short8*)&eh[((C0 + ct * 16 + col) << 7) + ((kb ^ col) << 3)];
      #pragma unroll
      for (int rt = 0; rt < 2; ++rt)
        #pragma unroll
        for (int ct = 0; ct < 2; ++ct)
          acc[rt][ct] = __builtin_amdgcn_mfma_f32_16x16x32_bf16(ah[rt], bh[ct], acc[rt][ct], 0, 0, 0);
    }
    const int c0g = ch * 64;
    #pragma unroll
    for (int ct = 0; ct < 2; ++ct) {
      const float e2v = e2f[c0g + C0 + ct * 16 + col];
      #pragma unroll
      for (int rt = 0; rt < 2; ++rt)
        #pragma unroll
        for (int r = 0; r < 4; ++r) {
          const float s = e2v - 2.0f * acc[rt][ct][r];
          runmin[rt * 4 + r] = fminf(runmin[rt * 4 + r], s);
        }
    }
  }
  // ---- row-global min reduce (32 lanes per row across 2 waves) ----
  __syncthreads();
  #pragma unroll
  for (int rt = 0; rt < 2; ++rt)
    #pragma unroll
    for (int r = 0; r < 4; ++r)
      sred[(R0 + rt * 16 + quad * 4 + r) * 32 + (wv & 1) * 16 + col] = runmin[rt * 4 + r];
  __syncthreads();
  if (tid < 64) {
    float m = sred[tid * 32];
    for (int j = 1; j < 32; ++j) m = fminf(m, sred[tid * 32 + j]);
    seed[tid] = m;
  }
  __syncthreads();
  float thresh[8];
  #pragma unroll
  for (int rt = 0; rt < 2; ++rt)
    #pragma unroll
    for (int r = 0; r < 4; ++r) {
      const int row = R0 + rt * 16 + quad * 4 + r;
      thresh[rt * 4 + r] = seed[row] + marg[row];
    }
  if (tid < 64) cnt[tid] = 0;

  // ---- Sweep B: identical recompute, margin-gated append ----
  for (int ch = 0; ch < 32; ++ch) {
    __syncthreads();
    #pragma unroll
    for (int sw = 0; sw < 4; ++sw) {
      const int s = sw * 256 + tid;
      const int c = s >> 4, kbp = s & 15;
      const int kb = kbp ^ (c & 15);
      ((uint4*)eh)[s] = *(const uint4*)(cbh + (((size_t)(ch * 64 + c)) << 7) + (kb << 3));
    }
    __syncthreads();
    float4v acc[2][2];
    #pragma unroll
    for (int rt = 0; rt < 2; ++rt)
      #pragma unroll
      for (int ct = 0; ct < 2; ++ct) acc[rt][ct] = vzero;
    #pragma unroll
    for (int ks = 0; ks < 4; ++ks) {
      const int kb = ks * 4 + quad;
      short8 ah[2], bh[2];
      #pragma unroll
      for (int rt = 0; rt < 2; ++rt)
        ah[rt] = *(const short8*)&zh[((R0 + rt * 16 + col) << 7) + ((kb ^ col) << 3)];
      #pragma unroll
      for (int ct = 0; ct < 2; ++ct)
        bh[ct] = *(const short8*)&eh[((C0 + ct * 16 + col) << 7) + ((kb ^ col) << 3)];
      #pragma unroll
      for (int rt = 0; rt < 2; ++rt)
        #pragma unroll
        for (int ct = 0; ct < 2; ++ct)
          acc[rt][ct] = __builtin_amdgcn_mfma_f32_16x16x32_bf16(ah[rt], bh[ct], acc[rt][ct], 0, 0, 0);
    }
    const int c0g = ch * 64;
    #pragma unroll
    for (int ct = 0; ct < 2; ++ct) {
      const float e2v = e2f[c0g + C0 + ct * 16 + col];
      const int kg0 = c0g + C0 + ct * 16 + col;
      #pragma unroll
      for (int rt = 0; rt < 2; ++rt)
        #pragma unroll
        for (int r = 0; r < 4; ++r) {
          const float s = e2v - 2.0f * acc[rt][ct][r];
          if (s < thresh[rt * 4 + r]) {
            const int rl = R0 + rt * 16 + quad * 4 + r;
            const int pos = atomicAdd(&cnt[rl], 1);
            if (pos < 16) candL[rl * 16 + pos] = (ushort)kg0;
          }
        }
    }
  }
  __syncthreads();
  if (tid < 64) {
    const int n = n0 + tid;
    candcnt[n] = cnt[tid];
    uint4* dst = (uint4*)(cand_g + (size_t)n * 16);
    const uint4* src = (const uint4*)(candL + tid * 16);
    dst[0] = src[0];
    dst[1] = src[1];
  }
}

// Phase 2: exact np-replica rescore (R2-verified formula) + f64 loss partials.
__global__ __launch_bounds__(256)
void rescore_kernel(const float* __restrict__ z, const float* __restrict__ cb,
                    const float* __restrict__ e2f, const float* __restrict__ Arow,
                    const ushort* __restrict__ cand_g, const int* __restrict__ candcnt,
                    int* __restrict__ idxbuf, int* __restrict__ counts,
                    float* __restrict__ out_idx, double* __restrict__ part) {
  const int tid = threadIdx.x;
  const int n = blockIdx.x * 256 + tid;           // 256 blocks
  const int c = candcnt[n];
  double sq = 0.0;
  if (c >= 1 && c <= 16) {                        // fallback handles the rest
    const int b = n >> 10, t = n & 1023;
    const float* zb = z + (size_t)b * DT + t;
    const float A = Arow[n];
    float best = 1e30f;
    int bk = Kk;
    for (int j = 0; j < c; ++j) {
      const int k = cand_g[(size_t)n * 16 + j];
      const float* e = cb + (size_t)k * Dd;
      double acc = 0.0;
      #pragma unroll 8
      for (int d = 0; d < 128; d += 4) {
        const float4 ev = *(const float4*)(e + d);
        acc += (double)zb[(d + 0) * Tt] * (double)ev.x;
        acc += (double)zb[(d + 1) * Tt] * (double)ev.y;
        acc += (double)zb[(d + 2) * Tt] * (double)ev.z;
        acc += (double)zb[(d + 3) * Tt] * (double)ev.w;
      }
      const float m32 = (float)acc;
      const float X = __fsub_rn(A, __fmul_rn(2.0f, m32));
      const float Dq = __fadd_rn(X, e2f[k]);
      if (Dq < best || (Dq == best && k < bk)) { best = Dq; bk = k; }
    }
    idxbuf[n] = bk;
    out_idx[n] = (float)bk;
    atomicAdd(&counts[bk], 1);
    const float* ew = cb + (size_t)bk * Dd;       // winner loss pass (caches hot)
    #pragma unroll 8
    for (int d = 0; d < 128; ++d) {
      const double dif = (double)zb[d * Tt] - (double)ew[d];
      sq += dif * dif;
    }
  }
  #pragma unroll
  for (int o = 32; o > 0; o >>= 1) sq += __shfl_down(sq, o, 64);
  __shared__ double w4[4];
  if ((tid & 63) == 0) w4[tid >> 6] = sq;
  __syncthreads();
  if (tid == 0) part[blockIdx.x] = w4[0] + w4[1] + w4[2] + w4[3];
}

// Fallback: full exact scan for rows with empty/overflowed lists (expected: none).
__global__ __launch_bounds__(256)
void fallback_kernel(const float* __restrict__ z, const float* __restrict__ cb,
                     const float* __restrict__ e2f, const float* __restrict__ Arow,
                     const int* __restrict__ candcnt, int* __restrict__ idxbuf,
                     int* __restrict__ counts, float* __restrict__ out_idx,
                     double* __restrict__ part) {
  __shared__ int flags[256];
  __shared__ int nf;
  __shared__ float xrow[128];
  __shared__ float rs[256];
  __shared__ int rk[256];
  const int tid = threadIdx.x;
  const int nb = blockIdx.x * 256;                // 256 blocks
  if (tid == 0) { nf = 0; part[256 + blockIdx.x] = 0.0; }
  __syncthreads();
  const int c = candcnt[nb + tid];
  const int bad = (c < 1 || c > 16) ? 1 : 0;
  flags[tid] = bad;
  if (bad) atomicAdd(&nf, 1);
  __syncthreads();
  if (nf == 0) return;                            // fast path
  double bsum = 0.0;
  for (int rr = 0; rr < 256; ++rr) {
    if (!flags[rr]) continue;                     // block-uniform
    const int n = nb + rr;
    const int b = n >> 10, t = n & 1023;
    if (tid < 128) xrow[tid] = z[(size_t)b * DT + (size_t)tid * Tt + t];
    __syncthreads();
    const float A = Arow[n];
    float best = 1e30f;
    int bk = Kk;
    for (int kk = tid * 8; kk < tid * 8 + 8; ++kk) {
      const float* e = cb + (size_t)kk * Dd;
      double acc = 0.0;
      for (int d = 0; d < 128; d += 4) {
        const float4 ev = *(const float4*)(e + d);
        acc += (double)xrow[d + 0] * (double)ev.x;
        acc += (double)xrow[d + 1] * (double)ev.y;
        acc += (double)xrow[d + 2] * (double)ev.z;
        acc += (double)xrow[d + 3] * (double)ev.w;
      }
      const float m32 = (float)acc;
      const float Dq = __fadd_rn(__fsub_rn(A, __fmul_rn(2.0f, m32)), e2f[kk]);
      if (Dq < best || (Dq == best && kk < bk)) { best = Dq; bk = kk; }
    }
    rs[tid] = best;
    rk[tid] = bk;
    __syncthreads();
    for (int o = 128; o > 0; o >>= 1) {
      if (tid < o) {
        if (rs[tid + o] < rs[tid] || (rs[tid + o] == rs[tid] && rk[tid + o] < rk[tid])) {
          rs[tid] = rs[tid + o];
          rk[tid] = rk[tid + o];
        }
      }
      __syncthreads();
    }
    if (tid == 0) {
      const int w = rk[0];
      idxbuf[n] = w;
      out_idx[n] = (float)w;
      atomicAdd(&counts[w], 1);
      const float* ew = cb + (size_t)w * Dd;
      for (int d = 0; d < 128; ++d) {
        const double dif = (double)xrow[d] - (double)ew[d];
        bsum += dif * dif;
      }
    }
    __syncthreads();
  }
  if (tid == 0) part[256 + blockIdx.x] = bsum;
}

// Gather z_q into (B,D,T) layout (z_q_st == z_q in value; no z read needed).
__global__ __launch_bounds__(256)
void gather_kernel(const float* __restrict__ cb, const int* __restrict__ idxbuf,
                   float* __restrict__ out0) {
  const int tid = threadIdx.x;
  const size_t o0 = ((size_t)blockIdx.x * 256 + tid) * 8;  // 4096 blocks
  const int b = (int)(o0 >> 17);
  const int dt = (int)(o0 & (size_t)(DT - 1));
  const int d = dt >> 10;
  const int t = dt & 1023;
  const int n = (b << 10) + t;
  float q[8];
  #pragma unroll
  for (int j = 0; j < 8; ++j) q[j] = cb[(size_t)idxbuf[n + j] * Dd + d];
  *(float4*)(out0 + o0)     = make_float4(q[0], q[1], q[2], q[3]);
  *(float4*)(out0 + o0 + 4) = make_float4(q[4], q[5], q[6], q[7]);
}

__global__ __launch_bounds__(256)
void finalize_kernel(const int* __restrict__ counts, const double* __restrict__ part,
                     float* __restrict__ out) {
  const int tid = threadIdx.x;
  __shared__ double red[256];
  double s = 0.0;
  for (int i = tid; i < 512; i += 256) s += part[i];
  red[tid] = s;
  __syncthreads();
  for (int o = 128; o > 0; o >>= 1) {
    if (tid < o) red[tid] += red[tid + o];
    __syncthreads();
  }
  const double loss = red[0];
  __syncthreads();
  double e = 0.0;
  for (int k = tid; k < 2048; k += 256) {
    const double p = (double)counts[k] / 65536.0;
    e += p * log(p + 1e-10);
  }
  red[tid] = e;
  __syncthreads();
  for (int o = 128; o > 0; o >>= 1) {
    if (tid < o) red[tid] += red[tid + o];
    __syncthreads();
  }
  if (tid == 0) {
    out[8388608] = (float)(0.25 * loss / 8388608.0);
    out[8388609] = (float)exp(-red[0]);
  }
}

extern "C" void kernel_launch(void* const* d_in, const int* in_sizes, int n_in,
                              void* d_out, int out_size, void* d_ws, size_t ws_size,
                              hipStream_t stream) {
  const float* z = (const float*)d_in[0];      // (B, D, T) fp32
  const float* cb = (const float*)d_in[1];     // (K, D) fp32
  float* out = (float*)d_out;                  // [z_q (8388608) | loss | perp | idx (65536)]
  char* ws = (char*)d_ws;
  ushort* cbh    = (ushort*)ws;
  float* e2f     = (float*)(ws + 524288);
  float* Arow    = (float*)(ws + 532480);
  int* idxbuf    = (int*)(ws + 794624);
  int* counts    = (int*)(ws + 1056768);
  double* part   = (double*)(ws + 1064960);
  ushort* cand_g = (ushort*)(ws + 1069056);
  int* candcnt   = (int*)(ws + 3166208);

  hipLaunchKernelGGL(setup_kernel,    dim3(1288), dim3(256), 0, stream, cb, z, cbh, e2f, Arow, counts);
  hipLaunchKernelGGL(score_kernel,    dim3(1024), dim3(256), 0, stream, z, cbh, e2f, Arow,
                     cand_g, candcnt);
  hipLaunchKernelGGL(rescore_kernel,  dim3(256),  dim3(256), 0, stream, z, cb, e2f, Arow,
                     cand_g, candcnt, idxbuf, counts, out + 8388610, part);
  hipLaunchKernelGGL(fallback_kernel, dim3(256),  dim3(256), 0, stream, z, cb, e2f, Arow,
                     candcnt, idxbuf, counts, out + 8388610, part);
  hipLaunchKernelGGL(gather_kernel,   dim3(4096), dim3(256), 0, stream, cb, idxbuf, out);
  hipLaunchKernelGGL(finalize_kernel, dim3(1),    dim3(256), 0, stream, counts, part, out);
}